// Round 10
// baseline (1200.908 us; speedup 1.0000x reference)
//
// HierarchicalPattern — rev9b. rev9 failed to COMPILE: __builtin_nontemporal_store
// rejects HIP's uint4 (HIP_vector_type class, not a native vector). Fixed with a
// native ext_vector_type(4) uint alias for the nt store; (void) on hipMemsetAsync.
// Theory unchanged from rev9: (1) per-lane sorted top-4 extract buffer (rescan
// only on rare lane exhaustion, execz-skipped); (2) nontemporal bulk output
// stores (stop evicting gfT from L2 -> FETCH 180->~50MB, WRITE 622->~250MB);
// (3) feat: merged halves + 4x8 tiles + split-K2 via atomicAdd (ws memset).
// I/O fp16 (confirmed R5); masked u16 0xFBFF (finite fp16+bf16; only NaN fails).
#include <hip/hip_runtime.h>
#include <hip/hip_fp16.h>
#include <cstdint>

#define SEQ 4096
#define NB 4
#define DMODEL 1024
#define ID 64
#define LW 16
#define GK 32
#define TQ 4

#define NEG_INF (-__builtin_inff())
#define MASKED4 0xFBFFFBFFu

typedef unsigned int uint32x4 __attribute__((ext_vector_type(4)));

__device__ __forceinline__ float2 h2f2(unsigned int u) {
    __half2 h = *reinterpret_cast<__half2*>(&u);
    return __half22float2(h);
}

__device__ __forceinline__ unsigned long long wave_max_u64(unsigned long long v) {
#pragma unroll
    for (int off = 32; off > 0; off >>= 1) {
        unsigned long long o = __shfl_xor(v, off, 64);
        v = (o > v) ? o : v;
    }
    return v;
}

// ---------------- Kernel 1: feat, merged halves, split-K2 --------------------
// grid 512: row-block = bid>>1 (64 rows), khalf = bid&1 (512 of K each).
// Block computes 64 rows x 128 cols (Wl||Wg) partials, atomicAdd into lf/gfT
// (ws zeroed by a memset node). Thread tile 4x8: 3 ds_read_b128 / 32 FMA.
__global__ __launch_bounds__(256)
void hp_feat_v9(const unsigned short* __restrict__ x,
                const unsigned short* __restrict__ Wl,
                const unsigned short* __restrict__ Wg,
                float* __restrict__ lf, float* __restrict__ gfT)
{
    __shared__ float xs[32][68];     // [k][row]
    __shared__ float ws[32][132];    // [k][col 0..127]
    __shared__ float trans[64][68];  // gf transpose staging

    const int tid = threadIdx.x;
    const long row0 = (long)(blockIdx.x >> 1) * 64;
    const int kbase = (blockIdx.x & 1) * 512;
    const int tx = tid & 15, ty = tid >> 4;

    float acc[4][8];
#pragma unroll
    for (int r = 0; r < 4; r++)
#pragma unroll
        for (int c = 0; c < 8; c++) acc[r][c] = 0.f;

    for (int kt = 0; kt < 16; kt++) {
        const int k0 = kbase + kt * 32;
        {   // x tile 64x32: one uint4 (8 fp16) per thread
            int r = tid >> 2, c8 = (tid & 3) * 8;
            uint4 v = *(const uint4*)(x + (row0 + r) * DMODEL + k0 + c8);
            float2 f;
            f = h2f2(v.x); xs[c8 + 0][r] = f.x; xs[c8 + 1][r] = f.y;
            f = h2f2(v.y); xs[c8 + 2][r] = f.x; xs[c8 + 3][r] = f.y;
            f = h2f2(v.z); xs[c8 + 4][r] = f.x; xs[c8 + 5][r] = f.y;
            f = h2f2(v.w); xs[c8 + 6][r] = f.x; xs[c8 + 7][r] = f.y;
        }
#pragma unroll
        for (int i = 0; i < 2; i++) {   // W tile 128x32: two uint4 per thread
            int idx = tid + 256 * i;
            int r = idx >> 2, c8 = (idx & 3) * 8;
            const unsigned short* Wp = (r < 64) ? (Wl + (long)r * DMODEL)
                                                : (Wg + (long)(r - 64) * DMODEL);
            uint4 v = *(const uint4*)(Wp + k0 + c8);
            float2 f;
            f = h2f2(v.x); ws[c8 + 0][r] = f.x; ws[c8 + 1][r] = f.y;
            f = h2f2(v.y); ws[c8 + 2][r] = f.x; ws[c8 + 3][r] = f.y;
            f = h2f2(v.z); ws[c8 + 4][r] = f.x; ws[c8 + 5][r] = f.y;
            f = h2f2(v.w); ws[c8 + 6][r] = f.x; ws[c8 + 7][r] = f.y;
        }
        __syncthreads();
#pragma unroll
        for (int kk = 0; kk < 32; kk++) {
            float4 a  = *(const float4*)&xs[kk][ty * 4];
            float4 b0 = *(const float4*)&ws[kk][tx * 8];
            float4 b1 = *(const float4*)&ws[kk][tx * 8 + 4];
            const float ar[4] = {a.x, a.y, a.z, a.w};
            const float bc[8] = {b0.x, b0.y, b0.z, b0.w, b1.x, b1.y, b1.z, b1.w};
#pragma unroll
            for (int r = 0; r < 4; r++)
#pragma unroll
                for (int c = 0; c < 8; c++)
                    acc[r][c] = fmaf(ar[r], bc[c], acc[r][c]);
        }
        __syncthreads();
    }

    if (tx < 8) {       // lf half: cols tx*8..+7
#pragma unroll
        for (int r = 0; r < 4; r++)
#pragma unroll
            for (int c = 0; c < 8; c++)
                atomicAdd(lf + (row0 + ty * 4 + r) * ID + tx * 8 + c, acc[r][c]);
    } else {            // gf half: stage transpose
#pragma unroll
        for (int r = 0; r < 4; r++)
#pragma unroll
            for (int c = 0; c < 8; c++)
                trans[(tx - 8) * 8 + c][ty * 4 + r] = acc[r][c];
    }
    __syncthreads();
    {   // cooperative gfT atomic stores: 64 cols x 64 seq
        const int b = (int)(row0 >> 12), s0 = (int)(row0 & 4095);
        const int col = tid >> 2, rs = (tid & 3) * 16;
        float* dst = gfT + ((long)b * ID + col) * SEQ + s0 + rs;
#pragma unroll
        for (int u = 0; u < 16; u++)
            atomicAdd(dst + u, trans[col][rs + u]);
    }
}

// ---------------- Kernel 2: TQ=4 queries per block ---------------------------
// Phase 1: outer-product scores in registers (proven v7/v8).
// Phase 2a: per-wave top-32 on packed u64 (bits(relu(s))+1)<<13 | (SEQ-k)
// (u64 order = value desc, index asc = JAX tie order) using a per-lane SORTED
// TOP-4 buffer: common iter = wave_max + shift; refill (rebuild top-4 of
// {p < floor}) only when a lane exhausts its 4 (rare, execz-skipped). floor =
// lane's last winning key, so {p < floor} is exactly its unextracted set.
// Phase 2b: wave w merges query w's 4x32 candidates. Output: nontemporal bulk
// MASKED stores (don't evict gfT from L2), then scatter zeros.
__global__ __launch_bounds__(256)
void hp_mask_v9(const float* __restrict__ lf, const float* __restrict__ gfT,
                unsigned short* __restrict__ out)
{
    __shared__ float qv[TQ][ID];
    __shared__ float lq[TQ][ID];
    __shared__ unsigned long long cand[TQ][4][GK];
    __shared__ int   sel[TQ][GK];
    __shared__ int   lsel[TQ][4];
    __shared__ int   lcnt[TQ];
    __shared__ float lsc[TQ][LW];

    const int tid = threadIdx.x;
    const int lane = tid & 63, w = tid >> 6;
    const int bid = blockIdx.x;
    const int b = (bid >> 1) & 3;
    const int q0 = (((bid >> 3) << 1) | (bid & 1)) * TQ;
    const float* gTb = gfT + (long)b * ID * SEQ;
    const float* lfb = lf + (long)b * SEQ * ID;

    {
        int d = tid >> 2, qi = tid & 3;
        qv[qi][d] = gTb[(long)d * SEQ + q0 + qi];
        int qi2 = tid >> 6, d2 = tid & 63;
        lq[qi2][d2] = lfb[(long)(q0 + qi2) * ID + d2];
    }
    __syncthreads();

    // ---- Phase 1: register-resident scores ----------------------------------
    float acc[4][4][TQ];
#pragma unroll
    for (int c = 0; c < 4; c++)
#pragma unroll
        for (int j = 0; j < 4; j++)
#pragma unroll
            for (int qi = 0; qi < TQ; qi++) acc[c][j][qi] = 0.f;

    for (int d = 0; d < ID; d++) {
        float qd[TQ];
#pragma unroll
        for (int qi = 0; qi < TQ; qi++) qd[qi] = qv[qi][d];
        const float4* rowp = (const float4*)(gTb + (long)d * SEQ);
#pragma unroll
        for (int c = 0; c < 4; c++) {
            float4 kv = rowp[c * 256 + tid];
#pragma unroll
            for (int qi = 0; qi < TQ; qi++) {
                acc[c][0][qi] = fmaf(kv.x, qd[qi], acc[c][0][qi]);
                acc[c][1][qi] = fmaf(kv.y, qd[qi], acc[c][1][qi]);
                acc[c][2][qi] = fmaf(kv.z, qd[qi], acc[c][2][qi]);
                acc[c][3][qi] = fmaf(kv.w, qd[qi], acc[c][3][qi]);
            }
        }
    }

    // ---- Phase 2a: per-wave top-32 via sorted top-4 buffer ------------------
#pragma unroll 1
    for (int qi = 0; qi < TQ; qi++) {
        const int q = q0 + qi;
        unsigned long long packed[16];
#pragma unroll
        for (int c = 0; c < 4; c++)
#pragma unroll
            for (int j = 0; j < 4; j++) {
                int k = 1024 * c + 4 * tid + j;
                float sv = acc[c][j][qi];
                bool banned = (k <= q) && (k >= q - (LW - 1));
                unsigned int u = banned ? 0u
                               : (__float_as_uint(fmaxf(sv, 0.f)) + 1u);
                packed[c * 4 + j] = ((unsigned long long)u << 13)
                                  | (unsigned long long)(SEQ - k);
            }
        // build sorted top-4 (b0>=b1>=b2>=b3), branchless insertion
        unsigned long long b0 = 0, b1 = 0, b2 = 0, b3 = 0;
#pragma unroll
        for (int i = 0; i < 16; i++) {
            unsigned long long p = packed[i];
            bool g0 = p > b0, g1 = p > b1, g2 = p > b2, g3 = p > b3;
            b3 = g3 ? (g2 ? b2 : p) : b3;
            b2 = g2 ? (g1 ? b1 : p) : b2;
            b1 = g1 ? (g0 ? b0 : p) : b1;
            b0 = g0 ? p : b0;
        }
        unsigned long long floorv = ~0ull;

#pragma unroll 1
        for (int it = 0; it < GK; it++) {
            unsigned long long m = wave_max_u64(b0);
            if (lane == 0) cand[qi][w][it] = m;
            if (b0 == m) {                  // unique winner lane
                floorv = m;
                b0 = b1; b1 = b2; b2 = b3; b3 = 0ull;
                if (b0 == 0ull) {           // rare refill: top-4 of {p < floor}
                    unsigned long long n0 = 0, n1 = 0, n2 = 0, n3 = 0;
#pragma unroll
                    for (int i = 0; i < 16; i++) {
                        unsigned long long p = packed[i];
                        p = (p < floorv) ? p : 0ull;
                        bool g0 = p > n0, g1 = p > n1, g2 = p > n2, g3 = p > n3;
                        n3 = g3 ? (g2 ? n2 : p) : n3;
                        n2 = g2 ? (g1 ? n1 : p) : n2;
                        n1 = g1 ? (g0 ? n0 : p) : n1;
                        n0 = g0 ? p : n0;
                    }
                    b0 = n0; b1 = n1; b2 = n2; b3 = n3;
                }
            }
        }
    }
    __syncthreads();

    // ---- Phase 2b: wave w merges query w's 128 candidates -------------------
    {
        const unsigned long long* cf = &cand[w][0][0];
        unsigned long long c0 = cf[lane], c1 = cf[64 + lane];
#pragma unroll 1
        for (int it = 0; it < GK; it++) {
            unsigned long long pm = (c0 > c1) ? c0 : c1;
            unsigned long long m = wave_max_u64(pm);
            if (c0 == m) c0 = 0ull;
            else if (c1 == m) c1 = 0ull;
            if (lane == 0) sel[w][it] = SEQ - (int)(m & 0x1FFFull);
        }
    }

    // ---- local window: 16 scores per query, stable top-ks -------------------
    if (tid < TQ * LW) {
        int qi = tid >> 4, wnd = tid & 15;
        int q = q0 + qi;
        int win = q - (LW - 1) + wnd;
        float v = NEG_INF;
        if (win >= 0) {
            const float4* kr = (const float4*)(lfb + (long)win * ID);
            float s = 0.f;
#pragma unroll
            for (int d = 0; d < 16; d++) {
                float4 kvv = kr[d];
                const float4 qd = *(const float4*)&lq[qi][d * 4];
                s = fmaf(kvv.x, qd.x, s); s = fmaf(kvv.y, qd.y, s);
                s = fmaf(kvv.z, qd.z, s); s = fmaf(kvv.w, qd.w, s);
            }
            v = fmaxf(s, 0.f);
        }
        lsc[qi][wnd] = v;
    }
    __syncthreads();
    if (tid < TQ) {
        int qi = tid, q = q0 + qi;
        int L = (q + 1 < LW) ? q + 1 : LW;
        int ks = L / 5; if (ks < 1) ks = 1;   // == max(1, int(L*0.2))
        lcnt[qi] = ks;
        for (int t = 0; t < ks; t++) {
            float best = NEG_INF; int bi = 0;
            for (int wnd = 0; wnd < LW; wnd++) {
                float v = lsc[qi][wnd];
                if (v > best) { best = v; bi = wnd; }  // strict > keeps lowest idx
            }
            lsc[qi][bi] = NEG_INF;
            lsel[qi][t] = q - (LW - 1) + bi;
        }
    }
    __syncthreads();

    // ---- output: nontemporal bulk MASKED rows, then scatter zeros -----------
    uint32x4* orow = (uint32x4*)(out + ((long)b * SEQ + q0) * SEQ);
    const uint32x4 m4 = {MASKED4, MASKED4, MASKED4, MASKED4};
#pragma unroll
    for (int i = 0; i < TQ * SEQ / 8 / 256; i++)
        __builtin_nontemporal_store(m4, &orow[i * 256 + tid]);
    __syncthreads();
    if (tid < TQ * GK) {
        int qi = tid >> 5;
        out[((long)b * SEQ + q0 + qi) * SEQ + sel[qi][tid & 31]] = 0;
    } else if (tid < TQ * GK + TQ * 4) {
        int t = tid - TQ * GK;
        int qi = t >> 2, j = t & 3;
        if (j < lcnt[qi])
            out[((long)b * SEQ + q0 + qi) * SEQ + lsel[qi][j]] = 0;
    }
}

extern "C" void kernel_launch(void* const* d_in, const int* in_sizes, int n_in,
                              void* d_out, int out_size, void* d_ws, size_t ws_size,
                              hipStream_t stream) {
    const unsigned short* x  = (const unsigned short*)d_in[0];
    const unsigned short* Wl = (const unsigned short*)d_in[1];
    // d_in[2] = W_medium: dead in the reference — skipped.
    const unsigned short* Wg = (const unsigned short*)d_in[3];
    unsigned short* out = (unsigned short*)d_out;

    float* lf  = (float*)d_ws;                        // 4 MiB, row-major
    float* gfT = lf + (long)NB * SEQ * ID;            // 4 MiB, [b][d][k]

    // zero lf+gfT for split-K atomic accumulation (ws is poisoned 0xAA)
    (void)hipMemsetAsync(d_ws, 0, (size_t)NB * SEQ * ID * 4 * 2, stream);
    hp_feat_v9<<<(NB * SEQ / 64) * 2, 256, 0, stream>>>(x, Wl, Wg, lf, gfT);
    hp_mask_v9<<<NB * SEQ / TQ, 256, 0, stream>>>(lf, gfT, out);
}

// Round 11
// 1083.265 us; speedup vs baseline: 1.1086x; 1.1086x over previous
//
// HierarchicalPattern — rev11. R10 falsified two theories: instr-cut in phase
// 2a (no change, VALUBusy ~70%) and nt bulk stores (FETCH/WRITE unchanged).
// Invariant R7-R10: FETCH+WRITE ~800MB and dur == hbm_bytes/1.05TB/s -> the
// mask kernel is HBM-traffic-bound at low effective BW. R6's flag-based
// single-pass row write had WRITE == output size exactly (131072 KB) and
// FETCH 26MB; the R7+ bulk-fill + 2-byte scatter is the traffic source
// (partial-line RMW + gfT eviction churn). Fix: single-pass flag-select row
// writes (16 KiB LDS byte flags, nontemporal). Feat: revert to proven R8
// (split-K atomics regressed total by ~100us). I/O fp16; masked 0xFBFF.
#include <hip/hip_runtime.h>
#include <hip/hip_fp16.h>
#include <cstdint>

#define SEQ 4096
#define NB 4
#define DMODEL 1024
#define ID 64
#define LW 16
#define GK 32
#define TQ 4

#define NEG_INF (-__builtin_inff())
#define MASKED_U 0x0000FBFFu
#define ZERO_U   0x00000000u

typedef unsigned int uint32x4 __attribute__((ext_vector_type(4)));

__device__ __forceinline__ float2 h2f2(unsigned int u) {
    __half2 h = *reinterpret_cast<__half2*>(&u);
    return __half22float2(h);
}

__device__ __forceinline__ unsigned long long wave_max_u64(unsigned long long v) {
#pragma unroll
    for (int off = 32; off > 0; off >>= 1) {
        unsigned long long o = __shfl_xor(v, off, 64);
        v = (o > v) ? o : v;
    }
    return v;
}

// ---------------- Kernel 1: lf rows + gfT (proven R8 version) ----------------
__global__ __launch_bounds__(256)
void hp_feat_v11(const unsigned short* __restrict__ x,
                 const unsigned short* __restrict__ Wl,
                 const unsigned short* __restrict__ Wg,
                 float* __restrict__ lf, float* __restrict__ gfT)
{
    __shared__ float xs[32][68];
    __shared__ float ws[32][68];
    __shared__ float trans[64][68];

    const int tid = threadIdx.x;
    const int half = blockIdx.x & 1;
    const long row0 = (long)(blockIdx.x >> 1) * 64;
    const unsigned short* W = half ? Wg : Wl;
    const int tx = tid & 15, ty = tid >> 4;

    float acc[4][4];
#pragma unroll
    for (int r = 0; r < 4; r++)
#pragma unroll
        for (int c = 0; c < 4; c++) acc[r][c] = 0.f;

    for (int k0 = 0; k0 < DMODEL; k0 += 32) {
        {
            int r = tid >> 2, c8 = (tid & 3) * 8;
            uint4 v = *(const uint4*)(x + (row0 + r) * DMODEL + k0 + c8);
            float2 f;
            f = h2f2(v.x); xs[c8 + 0][r] = f.x; xs[c8 + 1][r] = f.y;
            f = h2f2(v.y); xs[c8 + 2][r] = f.x; xs[c8 + 3][r] = f.y;
            f = h2f2(v.z); xs[c8 + 4][r] = f.x; xs[c8 + 5][r] = f.y;
            f = h2f2(v.w); xs[c8 + 6][r] = f.x; xs[c8 + 7][r] = f.y;
        }
        {
            int r = tid >> 2, c8 = (tid & 3) * 8;
            uint4 v = *(const uint4*)(W + (long)r * DMODEL + k0 + c8);
            float2 f;
            f = h2f2(v.x); ws[c8 + 0][r] = f.x; ws[c8 + 1][r] = f.y;
            f = h2f2(v.y); ws[c8 + 2][r] = f.x; ws[c8 + 3][r] = f.y;
            f = h2f2(v.z); ws[c8 + 4][r] = f.x; ws[c8 + 5][r] = f.y;
            f = h2f2(v.w); ws[c8 + 6][r] = f.x; ws[c8 + 7][r] = f.y;
        }
        __syncthreads();
#pragma unroll
        for (int kk = 0; kk < 32; kk++) {
            float4 a  = *(const float4*)&xs[kk][ty * 4];
            float4 bv = *(const float4*)&ws[kk][tx * 4];
            const float ar[4] = {a.x, a.y, a.z, a.w};
            const float bc[4] = {bv.x, bv.y, bv.z, bv.w};
#pragma unroll
            for (int r = 0; r < 4; r++)
#pragma unroll
                for (int c = 0; c < 4; c++)
                    acc[r][c] = fmaf(ar[r], bc[c], acc[r][c]);
        }
        __syncthreads();
    }

    if (!half) {
#pragma unroll
        for (int r = 0; r < 4; r++) {
            float4 st = make_float4(acc[r][0], acc[r][1], acc[r][2], acc[r][3]);
            *(float4*)(lf + (row0 + ty * 4 + r) * ID + tx * 4) = st;
        }
    } else {
#pragma unroll
        for (int r = 0; r < 4; r++)
#pragma unroll
            for (int c = 0; c < 4; c++)
                trans[tx * 4 + c][ty * 4 + r] = acc[r][c];
        __syncthreads();
        const int b = (int)(row0 >> 12), s0 = (int)(row0 & 4095);
        const int col = tid >> 2, rs = (tid & 3) * 16;
        float* dst = gfT + ((long)b * ID + col) * SEQ + s0 + rs;
#pragma unroll
        for (int u = 0; u < 4; u++)
            *(float4*)(dst + 4 * u) = *(const float4*)&trans[col][rs + 4 * u];
    }
}

// ---------------- Kernel 2: TQ=4 queries per block ---------------------------
// Phase 1: outer-product register scores (proven v7+). Phase 2a: per-wave
// top-32 with sorted top-4 buffer (proven v10). Phase 2b: per-wave merge.
// Output: LDS byte flags (16 KiB, 4 rows), SINGLE-pass flag-select nt writes
// -> WRITE == output bytes exactly (R6-proven pattern), gfT stays L2-resident.
__global__ __launch_bounds__(256)
void hp_mask_v11(const float* __restrict__ lf, const float* __restrict__ gfT,
                 unsigned short* __restrict__ out)
{
    __shared__ float qv[TQ][ID];
    __shared__ float lq[TQ][ID];
    __shared__ unsigned long long cand[TQ][4][GK];
    __shared__ int   sel[TQ][GK];
    __shared__ int   lsel[TQ][4];
    __shared__ int   lcnt[TQ];
    __shared__ float lsc[TQ][LW];
    __shared__ unsigned int flags32[TQ * SEQ / 4];   // 16 KiB byte flags

    const int tid = threadIdx.x;
    const int lane = tid & 63, w = tid >> 6;
    const int bid = blockIdx.x;
    const int b = (bid >> 1) & 3;
    const int q0 = (((bid >> 3) << 1) | (bid & 1)) * TQ;
    const float* gTb = gfT + (long)b * ID * SEQ;
    const float* lfb = lf + (long)b * SEQ * ID;

    {
        int d = tid >> 2, qi = tid & 3;
        qv[qi][d] = gTb[(long)d * SEQ + q0 + qi];
        int qi2 = tid >> 6, d2 = tid & 63;
        lq[qi2][d2] = lfb[(long)(q0 + qi2) * ID + d2];
    }
#pragma unroll
    for (int i = 0; i < TQ * SEQ / 4 / 256; i++)     // 16 iters
        flags32[i * 256 + tid] = 0u;
    __syncthreads();

    // ---- Phase 1: register-resident scores ----------------------------------
    float acc[4][4][TQ];
#pragma unroll
    for (int c = 0; c < 4; c++)
#pragma unroll
        for (int j = 0; j < 4; j++)
#pragma unroll
            for (int qi = 0; qi < TQ; qi++) acc[c][j][qi] = 0.f;

    for (int d = 0; d < ID; d++) {
        float qd[TQ];
#pragma unroll
        for (int qi = 0; qi < TQ; qi++) qd[qi] = qv[qi][d];
        const float4* rowp = (const float4*)(gTb + (long)d * SEQ);
#pragma unroll
        for (int c = 0; c < 4; c++) {
            float4 kv = rowp[c * 256 + tid];
#pragma unroll
            for (int qi = 0; qi < TQ; qi++) {
                acc[c][0][qi] = fmaf(kv.x, qd[qi], acc[c][0][qi]);
                acc[c][1][qi] = fmaf(kv.y, qd[qi], acc[c][1][qi]);
                acc[c][2][qi] = fmaf(kv.z, qd[qi], acc[c][2][qi]);
                acc[c][3][qi] = fmaf(kv.w, qd[qi], acc[c][3][qi]);
            }
        }
    }

    // ---- Phase 2a: per-wave top-32 via sorted top-4 buffer ------------------
#pragma unroll 1
    for (int qi = 0; qi < TQ; qi++) {
        const int q = q0 + qi;
        unsigned long long packed[16];
#pragma unroll
        for (int c = 0; c < 4; c++)
#pragma unroll
            for (int j = 0; j < 4; j++) {
                int k = 1024 * c + 4 * tid + j;
                float sv = acc[c][j][qi];
                bool banned = (k <= q) && (k >= q - (LW - 1));
                unsigned int u = banned ? 0u
                               : (__float_as_uint(fmaxf(sv, 0.f)) + 1u);
                packed[c * 4 + j] = ((unsigned long long)u << 13)
                                  | (unsigned long long)(SEQ - k);
            }
        unsigned long long b0 = 0, b1 = 0, b2 = 0, b3 = 0;
#pragma unroll
        for (int i = 0; i < 16; i++) {
            unsigned long long p = packed[i];
            bool g0 = p > b0, g1 = p > b1, g2 = p > b2, g3 = p > b3;
            b3 = g3 ? (g2 ? b2 : p) : b3;
            b2 = g2 ? (g1 ? b1 : p) : b2;
            b1 = g1 ? (g0 ? b0 : p) : b1;
            b0 = g0 ? p : b0;
        }
        unsigned long long floorv = ~0ull;

#pragma unroll 1
        for (int it = 0; it < GK; it++) {
            unsigned long long m = wave_max_u64(b0);
            if (lane == 0) cand[qi][w][it] = m;
            if (b0 == m) {
                floorv = m;
                b0 = b1; b1 = b2; b2 = b3; b3 = 0ull;
                if (b0 == 0ull) {           // rare refill
                    unsigned long long n0 = 0, n1 = 0, n2 = 0, n3 = 0;
#pragma unroll
                    for (int i = 0; i < 16; i++) {
                        unsigned long long p = packed[i];
                        p = (p < floorv) ? p : 0ull;
                        bool g0 = p > n0, g1 = p > n1, g2 = p > n2, g3 = p > n3;
                        n3 = g3 ? (g2 ? n2 : p) : n3;
                        n2 = g2 ? (g1 ? n1 : p) : n2;
                        n1 = g1 ? (g0 ? n0 : p) : n1;
                        n0 = g0 ? p : n0;
                    }
                    b0 = n0; b1 = n1; b2 = n2; b3 = n3;
                }
            }
        }
    }
    __syncthreads();

    // ---- Phase 2b: wave w merges query w's 128 candidates -------------------
    {
        const unsigned long long* cf = &cand[w][0][0];
        unsigned long long c0 = cf[lane], c1 = cf[64 + lane];
#pragma unroll 1
        for (int it = 0; it < GK; it++) {
            unsigned long long pm = (c0 > c1) ? c0 : c1;
            unsigned long long m = wave_max_u64(pm);
            if (c0 == m) c0 = 0ull;
            else if (c1 == m) c1 = 0ull;
            if (lane == 0) sel[w][it] = SEQ - (int)(m & 0x1FFFull);
        }
    }

    // ---- local window: 16 scores per query, stable top-ks -------------------
    if (tid < TQ * LW) {
        int qi = tid >> 4, wnd = tid & 15;
        int q = q0 + qi;
        int win = q - (LW - 1) + wnd;
        float v = NEG_INF;
        if (win >= 0) {
            const float4* kr = (const float4*)(lfb + (long)win * ID);
            float s = 0.f;
#pragma unroll
            for (int d = 0; d < 16; d++) {
                float4 kvv = kr[d];
                const float4 qd = *(const float4*)&lq[qi][d * 4];
                s = fmaf(kvv.x, qd.x, s); s = fmaf(kvv.y, qd.y, s);
                s = fmaf(kvv.z, qd.z, s); s = fmaf(kvv.w, qd.w, s);
            }
            v = fmaxf(s, 0.f);
        }
        lsc[qi][wnd] = v;
    }
    __syncthreads();
    if (tid < TQ) {
        int qi = tid, q = q0 + qi;
        int L = (q + 1 < LW) ? q + 1 : LW;
        int ks = L / 5; if (ks < 1) ks = 1;   // == max(1, int(L*0.2))
        lcnt[qi] = ks;
        for (int t = 0; t < ks; t++) {
            float best = NEG_INF; int bi = 0;
            for (int wnd = 0; wnd < LW; wnd++) {
                float v = lsc[qi][wnd];
                if (v > best) { best = v; bi = wnd; }
            }
            lsc[qi][bi] = NEG_INF;
            lsel[qi][t] = q - (LW - 1) + bi;
        }
    }
    __syncthreads();

    // ---- set flags (LDS, no global RMW) -------------------------------------
    if (tid < TQ * GK) {
        int qi = tid >> 5;
        ((unsigned char*)flags32)[qi * SEQ + sel[qi][tid & 31]] = 1;
    } else if (tid < TQ * GK + TQ * 4) {
        int t = tid - TQ * GK;
        int qi = t >> 2, j = t & 3;
        if (j < lcnt[qi])
            ((unsigned char*)flags32)[qi * SEQ + lsel[qi][j]] = 1;
    }
    __syncthreads();

    // ---- single-pass flag-select row write, nontemporal ---------------------
    uint32x4* orow = (uint32x4*)(out + ((long)b * SEQ + q0) * SEQ);
#pragma unroll
    for (int i = 0; i < TQ * SEQ / 8 / 256; i++) {   // 8 iters, 8 u16/thread
        int u8 = i * 256 + tid;                      // unit of 8 outputs
        unsigned int f0 = flags32[2 * u8 + 0];       // flags for elems 0..3
        unsigned int f1 = flags32[2 * u8 + 1];       // flags for elems 4..7
        uint32x4 v;
        v.x = ((f0 & 0x000000FFu) ? ZERO_U : MASKED_U)
            | (((f0 & 0x0000FF00u) ? ZERO_U : MASKED_U) << 16);
        v.y = ((f0 & 0x00FF0000u) ? ZERO_U : MASKED_U)
            | (((f0 & 0xFF000000u) ? ZERO_U : MASKED_U) << 16);
        v.z = ((f1 & 0x000000FFu) ? ZERO_U : MASKED_U)
            | (((f1 & 0x0000FF00u) ? ZERO_U : MASKED_U) << 16);
        v.w = ((f1 & 0x00FF0000u) ? ZERO_U : MASKED_U)
            | (((f1 & 0xFF000000u) ? ZERO_U : MASKED_U) << 16);
        __builtin_nontemporal_store(v, &orow[u8]);
    }
}

extern "C" void kernel_launch(void* const* d_in, const int* in_sizes, int n_in,
                              void* d_out, int out_size, void* d_ws, size_t ws_size,
                              hipStream_t stream) {
    const unsigned short* x  = (const unsigned short*)d_in[0];
    const unsigned short* Wl = (const unsigned short*)d_in[1];
    // d_in[2] = W_medium: dead in the reference — skipped.
    const unsigned short* Wg = (const unsigned short*)d_in[3];
    unsigned short* out = (unsigned short*)d_out;

    float* lf  = (float*)d_ws;                        // 4 MiB, row-major
    float* gfT = lf + (long)NB * SEQ * ID;            // 4 MiB, [b][d][k]

    hp_feat_v11<<<(NB * SEQ / 64) * 2, 256, 0, stream>>>(x, Wl, Wg, lf, gfT);
    hp_mask_v11<<<NB * SEQ / TQ, 256, 0, stream>>>(lf, gfT, out);
}

// Round 12
// 1077.202 us; speedup vs baseline: 1.1148x; 1.0056x over previous
//
// HierarchicalPattern — rev12. R11 falsified the write-pattern theory: R6's
// exact single-pass flag-select write reproduced in the R8+ structure left
// FETCH/WRITE/dur unchanged (177MB/622MB/793us). The select work and output
// stream are entangled in one dispatch; counters can't attribute. This rev
// SPLITS them: select kernel (scores+top-k -> 2.6MB sel lists in ws, ~zero
// output traffic, LDS 23.5->7KB so occupancy 3.5->~8 blk/CU) + write kernel
// (lists -> 128MiB mask, pure write-bound). Feat unchanged (proven R8).
// I/O fp16 (confirmed R5); masked u16 0xFBFF (finite fp16+bf16).
#include <hip/hip_runtime.h>
#include <hip/hip_fp16.h>
#include <cstdint>

#define SEQ 4096
#define NB 4
#define DMODEL 1024
#define ID 64
#define LW 16
#define GK 32
#define TQ 4
#define SELW 40          // ints per row in sel list: 32 global, [32]=lcnt, 33..35 local

#define NEG_INF (-__builtin_inff())
#define MASKED_U 0x0000FBFFu
#define ZERO_U   0x00000000u

typedef unsigned int uint32x4 __attribute__((ext_vector_type(4)));

__device__ __forceinline__ float2 h2f2(unsigned int u) {
    __half2 h = *reinterpret_cast<__half2*>(&u);
    return __half22float2(h);
}

__device__ __forceinline__ unsigned long long wave_max_u64(unsigned long long v) {
#pragma unroll
    for (int off = 32; off > 0; off >>= 1) {
        unsigned long long o = __shfl_xor(v, off, 64);
        v = (o > v) ? o : v;
    }
    return v;
}

// ---------------- Kernel 1: lf rows + gfT (proven R8 version) ----------------
__global__ __launch_bounds__(256)
void hp_feat_v12(const unsigned short* __restrict__ x,
                 const unsigned short* __restrict__ Wl,
                 const unsigned short* __restrict__ Wg,
                 float* __restrict__ lf, float* __restrict__ gfT)
{
    __shared__ float xs[32][68];
    __shared__ float ws[32][68];
    __shared__ float trans[64][68];

    const int tid = threadIdx.x;
    const int half = blockIdx.x & 1;
    const long row0 = (long)(blockIdx.x >> 1) * 64;
    const unsigned short* W = half ? Wg : Wl;
    const int tx = tid & 15, ty = tid >> 4;

    float acc[4][4];
#pragma unroll
    for (int r = 0; r < 4; r++)
#pragma unroll
        for (int c = 0; c < 4; c++) acc[r][c] = 0.f;

    for (int k0 = 0; k0 < DMODEL; k0 += 32) {
        {
            int r = tid >> 2, c8 = (tid & 3) * 8;
            uint4 v = *(const uint4*)(x + (row0 + r) * DMODEL + k0 + c8);
            float2 f;
            f = h2f2(v.x); xs[c8 + 0][r] = f.x; xs[c8 + 1][r] = f.y;
            f = h2f2(v.y); xs[c8 + 2][r] = f.x; xs[c8 + 3][r] = f.y;
            f = h2f2(v.z); xs[c8 + 4][r] = f.x; xs[c8 + 5][r] = f.y;
            f = h2f2(v.w); xs[c8 + 6][r] = f.x; xs[c8 + 7][r] = f.y;
        }
        {
            int r = tid >> 2, c8 = (tid & 3) * 8;
            uint4 v = *(const uint4*)(W + (long)r * DMODEL + k0 + c8);
            float2 f;
            f = h2f2(v.x); ws[c8 + 0][r] = f.x; ws[c8 + 1][r] = f.y;
            f = h2f2(v.y); ws[c8 + 2][r] = f.x; ws[c8 + 3][r] = f.y;
            f = h2f2(v.z); ws[c8 + 4][r] = f.x; ws[c8 + 5][r] = f.y;
            f = h2f2(v.w); ws[c8 + 6][r] = f.x; ws[c8 + 7][r] = f.y;
        }
        __syncthreads();
#pragma unroll
        for (int kk = 0; kk < 32; kk++) {
            float4 a  = *(const float4*)&xs[kk][ty * 4];
            float4 bv = *(const float4*)&ws[kk][tx * 4];
            const float ar[4] = {a.x, a.y, a.z, a.w};
            const float bc[4] = {bv.x, bv.y, bv.z, bv.w};
#pragma unroll
            for (int r = 0; r < 4; r++)
#pragma unroll
                for (int c = 0; c < 4; c++)
                    acc[r][c] = fmaf(ar[r], bc[c], acc[r][c]);
        }
        __syncthreads();
    }

    if (!half) {
#pragma unroll
        for (int r = 0; r < 4; r++) {
            float4 st = make_float4(acc[r][0], acc[r][1], acc[r][2], acc[r][3]);
            *(float4*)(lf + (row0 + ty * 4 + r) * ID + tx * 4) = st;
        }
    } else {
#pragma unroll
        for (int r = 0; r < 4; r++)
#pragma unroll
            for (int c = 0; c < 4; c++)
                trans[tx * 4 + c][ty * 4 + r] = acc[r][c];
        __syncthreads();
        const int b = (int)(row0 >> 12), s0 = (int)(row0 & 4095);
        const int col = tid >> 2, rs = (tid & 3) * 16;
        float* dst = gfT + ((long)b * ID + col) * SEQ + s0 + rs;
#pragma unroll
        for (int u = 0; u < 4; u++)
            *(float4*)(dst + 4 * u) = *(const float4*)&trans[col][rs + 4 * u];
    }
}

// ---------------- Kernel 2: SELECT (no mask output) --------------------------
// Phase 1: outer-product register scores; Phase 2a: per-wave top-32 (sorted
// top-4 buffer, exact refill); Phase 2b: per-wave merge; local window topks.
// Emits per-row list: rowsel[row][0..31]=global idx, [32]=lcnt, [33..35]=local.
__global__ __launch_bounds__(256)
void hp_sel_v12(const float* __restrict__ lf, const float* __restrict__ gfT,
                int* __restrict__ rowsel)
{
    __shared__ float qv[TQ][ID];
    __shared__ float lq[TQ][ID];
    __shared__ unsigned long long cand[TQ][4][GK];
    __shared__ int   sel[TQ][GK];
    __shared__ int   lsel[TQ][4];
    __shared__ int   lcnt[TQ];
    __shared__ float lsc[TQ][LW];

    const int tid = threadIdx.x;
    const int lane = tid & 63, w = tid >> 6;
    const int bid = blockIdx.x;
    const int b = (bid >> 1) & 3;
    const int q0 = (((bid >> 3) << 1) | (bid & 1)) * TQ;
    const float* gTb = gfT + (long)b * ID * SEQ;
    const float* lfb = lf + (long)b * SEQ * ID;

    {
        int d = tid >> 2, qi = tid & 3;
        qv[qi][d] = gTb[(long)d * SEQ + q0 + qi];
        int qi2 = tid >> 6, d2 = tid & 63;
        lq[qi2][d2] = lfb[(long)(q0 + qi2) * ID + d2];
    }
    __syncthreads();

    // ---- Phase 1 ----
    float acc[4][4][TQ];
#pragma unroll
    for (int c = 0; c < 4; c++)
#pragma unroll
        for (int j = 0; j < 4; j++)
#pragma unroll
            for (int qi = 0; qi < TQ; qi++) acc[c][j][qi] = 0.f;

    for (int d = 0; d < ID; d++) {
        float qd[TQ];
#pragma unroll
        for (int qi = 0; qi < TQ; qi++) qd[qi] = qv[qi][d];
        const float4* rowp = (const float4*)(gTb + (long)d * SEQ);
#pragma unroll
        for (int c = 0; c < 4; c++) {
            float4 kv = rowp[c * 256 + tid];
#pragma unroll
            for (int qi = 0; qi < TQ; qi++) {
                acc[c][0][qi] = fmaf(kv.x, qd[qi], acc[c][0][qi]);
                acc[c][1][qi] = fmaf(kv.y, qd[qi], acc[c][1][qi]);
                acc[c][2][qi] = fmaf(kv.z, qd[qi], acc[c][2][qi]);
                acc[c][3][qi] = fmaf(kv.w, qd[qi], acc[c][3][qi]);
            }
        }
    }

    // ---- Phase 2a: per-wave top-32 via sorted top-4 buffer ------------------
#pragma unroll 1
    for (int qi = 0; qi < TQ; qi++) {
        const int q = q0 + qi;
        unsigned long long packed[16];
#pragma unroll
        for (int c = 0; c < 4; c++)
#pragma unroll
            for (int j = 0; j < 4; j++) {
                int k = 1024 * c + 4 * tid + j;
                float sv = acc[c][j][qi];
                bool banned = (k <= q) && (k >= q - (LW - 1));
                unsigned int u = banned ? 0u
                               : (__float_as_uint(fmaxf(sv, 0.f)) + 1u);
                packed[c * 4 + j] = ((unsigned long long)u << 13)
                                  | (unsigned long long)(SEQ - k);
            }
        unsigned long long b0 = 0, b1 = 0, b2 = 0, b3 = 0;
#pragma unroll
        for (int i = 0; i < 16; i++) {
            unsigned long long p = packed[i];
            bool g0 = p > b0, g1 = p > b1, g2 = p > b2, g3 = p > b3;
            b3 = g3 ? (g2 ? b2 : p) : b3;
            b2 = g2 ? (g1 ? b1 : p) : b2;
            b1 = g1 ? (g0 ? b0 : p) : b1;
            b0 = g0 ? p : b0;
        }
        unsigned long long floorv = ~0ull;

#pragma unroll 1
        for (int it = 0; it < GK; it++) {
            unsigned long long m = wave_max_u64(b0);
            if (lane == 0) cand[qi][w][it] = m;
            if (b0 == m) {
                floorv = m;
                b0 = b1; b1 = b2; b2 = b3; b3 = 0ull;
                if (b0 == 0ull) {           // rare exact refill
                    unsigned long long n0 = 0, n1 = 0, n2 = 0, n3 = 0;
#pragma unroll
                    for (int i = 0; i < 16; i++) {
                        unsigned long long p = packed[i];
                        p = (p < floorv) ? p : 0ull;
                        bool g0 = p > n0, g1 = p > n1, g2 = p > n2, g3 = p > n3;
                        n3 = g3 ? (g2 ? n2 : p) : n3;
                        n2 = g2 ? (g1 ? n1 : p) : n2;
                        n1 = g1 ? (g0 ? n0 : p) : n1;
                        n0 = g0 ? p : n0;
                    }
                    b0 = n0; b1 = n1; b2 = n2; b3 = n3;
                }
            }
        }
    }
    __syncthreads();

    // ---- Phase 2b: wave w merges query w's 128 candidates -------------------
    {
        const unsigned long long* cf = &cand[w][0][0];
        unsigned long long c0 = cf[lane], c1 = cf[64 + lane];
#pragma unroll 1
        for (int it = 0; it < GK; it++) {
            unsigned long long pm = (c0 > c1) ? c0 : c1;
            unsigned long long m = wave_max_u64(pm);
            if (c0 == m) c0 = 0ull;
            else if (c1 == m) c1 = 0ull;
            if (lane == 0) sel[w][it] = SEQ - (int)(m & 0x1FFFull);
        }
    }

    // ---- local window ----
    if (tid < TQ * LW) {
        int qi = tid >> 4, wnd = tid & 15;
        int q = q0 + qi;
        int win = q - (LW - 1) + wnd;
        float v = NEG_INF;
        if (win >= 0) {
            const float4* kr = (const float4*)(lfb + (long)win * ID);
            float s = 0.f;
#pragma unroll
            for (int d = 0; d < 16; d++) {
                float4 kvv = kr[d];
                const float4 qd = *(const float4*)&lq[qi][d * 4];
                s = fmaf(kvv.x, qd.x, s); s = fmaf(kvv.y, qd.y, s);
                s = fmaf(kvv.z, qd.z, s); s = fmaf(kvv.w, qd.w, s);
            }
            v = fmaxf(s, 0.f);
        }
        lsc[qi][wnd] = v;
    }
    __syncthreads();
    if (tid < TQ) {
        int qi = tid, q = q0 + qi;
        int L = (q + 1 < LW) ? q + 1 : LW;
        int ks = L / 5; if (ks < 1) ks = 1;   // == max(1, int(L*0.2)); ks<=3
        lcnt[qi] = ks;
        for (int t = 0; t < ks; t++) {
            float best = NEG_INF; int bi = 0;
            for (int wnd = 0; wnd < LW; wnd++) {
                float v = lsc[qi][wnd];
                if (v > best) { best = v; bi = wnd; }  // strict > keeps lowest idx
            }
            lsc[qi][bi] = NEG_INF;
            lsel[qi][t] = q - (LW - 1) + bi;
        }
    }
    __syncthreads();

    // ---- emit per-row selection lists (tiny, coalesced-ish) -----------------
    const long row = (long)b * SEQ + q0;
    if (tid < TQ * GK) {                                  // 128 global indices
        int qi = tid >> 5;
        rowsel[(row + qi) * SELW + (tid & 31)] = sel[qi][tid & 31];
    } else if (tid < TQ * GK + TQ) {                      // 4 counts
        int qi = tid - TQ * GK;
        rowsel[(row + qi) * SELW + 32] = lcnt[qi];
    } else if (tid < TQ * GK + TQ + TQ * 3) {             // up to 12 local idx
        int t = tid - TQ * GK - TQ;
        int qi = t / 3, j = t % 3;
        rowsel[(row + qi) * SELW + 33 + j] = (j < lcnt[qi]) ? lsel[qi][j] : 0;
    }
}

// ---------------- Kernel 3: WRITE (pure output stream) -----------------------
// grid 4096 x 256: block handles 4 linear rows (32 KB). LDS byte flags from
// the row lists, then single-pass flag-select nontemporal uint32x4 stores.
__global__ __launch_bounds__(256)
void hp_write_v12(const int* __restrict__ rowsel, unsigned short* __restrict__ out)
{
    __shared__ unsigned int flags32[TQ * SEQ / 4];   // 16 KiB
    __shared__ int srow[TQ][SELW];

    const int tid = threadIdx.x;
    const long row0 = (long)blockIdx.x * TQ;

    if (tid < TQ * SELW)
        srow[tid / SELW][tid % SELW] = rowsel[row0 * SELW + tid];
#pragma unroll
    for (int i = 0; i < TQ * SEQ / 4 / 256; i++)
        flags32[i * 256 + tid] = 0u;
    __syncthreads();

    if (tid < TQ * GK) {
        int qi = tid >> 5;
        ((unsigned char*)flags32)[qi * SEQ + srow[qi][tid & 31]] = 1;
    } else if (tid < TQ * GK + TQ * 3) {
        int t = tid - TQ * GK;
        int qi = t / 3, j = t % 3;
        if (j < srow[qi][32])
            ((unsigned char*)flags32)[qi * SEQ + srow[qi][33 + j]] = 1;
    }
    __syncthreads();

    uint32x4* orow = (uint32x4*)(out + row0 * SEQ);
#pragma unroll
    for (int i = 0; i < TQ * SEQ / 8 / 256; i++) {   // 8 iters, 8 u16/thread
        int u8 = i * 256 + tid;
        unsigned int f0 = flags32[2 * u8 + 0];
        unsigned int f1 = flags32[2 * u8 + 1];
        uint32x4 v;
        v.x = ((f0 & 0x000000FFu) ? ZERO_U : MASKED_U)
            | (((f0 & 0x0000FF00u) ? ZERO_U : MASKED_U) << 16);
        v.y = ((f0 & 0x00FF0000u) ? ZERO_U : MASKED_U)
            | (((f0 & 0xFF000000u) ? ZERO_U : MASKED_U) << 16);
        v.z = ((f1 & 0x000000FFu) ? ZERO_U : MASKED_U)
            | (((f1 & 0x0000FF00u) ? ZERO_U : MASKED_U) << 16);
        v.w = ((f1 & 0x00FF0000u) ? ZERO_U : MASKED_U)
            | (((f1 & 0xFF000000u) ? ZERO_U : MASKED_U) << 16);
        __builtin_nontemporal_store(v, &orow[u8]);
    }
}

extern "C" void kernel_launch(void* const* d_in, const int* in_sizes, int n_in,
                              void* d_out, int out_size, void* d_ws, size_t ws_size,
                              hipStream_t stream) {
    const unsigned short* x  = (const unsigned short*)d_in[0];
    const unsigned short* Wl = (const unsigned short*)d_in[1];
    // d_in[2] = W_medium: dead in the reference — skipped.
    const unsigned short* Wg = (const unsigned short*)d_in[3];
    unsigned short* out = (unsigned short*)d_out;

    float* lf  = (float*)d_ws;                        // 4 MiB
    float* gfT = lf + (long)NB * SEQ * ID;            // 4 MiB
    int* rowsel = (int*)(gfT + (long)NB * SEQ * ID);  // 16384*40*4 = 2.62 MB

    hp_feat_v12<<<(NB * SEQ / 64) * 2, 256, 0, stream>>>(x, Wl, Wg, lf, gfT);
    hp_sel_v12<<<NB * SEQ / TQ, 256, 0, stream>>>(lf, gfT, rowsel);
    hp_write_v12<<<NB * SEQ / TQ, 256, 0, stream>>>(rowsel, out);
}